// Round 7
// baseline (30.181 us; speedup 1.0000x reference)
//
#include <hip/hip_runtime.h>
#include <cmath>

#define WS 11

typedef float v2f __attribute__((ext_vector_type(2)));

struct GaussPairs {
    unsigned long long gA[WS];   // (g/sqrt2, g/sqrt2) per tap — linear chain
    unsigned long long gS[WS];   // (g/2, g/2)        per tap — square chain
    unsigned long long c1c1;     // (C1, C1)
    unsigned long long c2c2;     // (C2, C2)
};

// ---- VOP3P packed-f32 helpers (gfx90a+/gfx950) ----
__device__ __forceinline__ v2f pk_fma_sg(unsigned long long g, v2f b, v2f c) {
    v2f d;
    asm("v_pk_fma_f32 %0, %1, %2, %3" : "=v"(d) : "s"(g), "v"(b), "v"(c));
    return d;
}
__device__ __forceinline__ v2f pk_mul(v2f a, v2f b) {
    v2f d;
    asm("v_pk_mul_f32 %0, %1, %2" : "=v"(d) : "v"(a), "v"(b));
    return d;
}
// (a.x+a.y, a.x-a.y)
__device__ __forceinline__ v2f pk_sumdiff(v2f a) {
    v2f d;
    asm("v_pk_add_f32 %0, %1, %1 op_sel:[0,1] op_sel_hi:[0,1] neg_hi:[0,1]"
        : "=v"(d) : "v"(a));
    return d;
}
__device__ __forceinline__ v2f pk_add_sg(v2f a, unsigned long long c) {
    v2f d;
    asm("v_pk_add_f32 %0, %1, %2" : "=v"(d) : "v"(a), "s"(c));
    return d;
}
__device__ __forceinline__ v2f pk_sub(v2f a, v2f b) {
    v2f d;
    asm("v_pk_add_f32 %0, %1, %2 neg_lo:[0,1] neg_hi:[0,1]"
        : "=v"(d) : "v"(a), "v"(b));
    return d;
}

// 16*3*512 = 24576 rows of 512 floats. One wave per row, 8 px/lane,
// 3 rows/wave. No shuffles: halo taps come from overlapping global loads
// (L1-cached); edge lanes clamp addresses and zero halo taps via a mask
// pair. 4-conv identity (u=p+q, v=p-q) packed as (u,v)/(u2,v2); Gaussian
// prescaled (1/sqrt2 linear, 1/2 square) so the epilogue is 0.5-free and
// fully packed.
__global__ __launch_bounds__(256) void ssim_row_kernel(
    const float* __restrict__ pred, const float* __restrict__ targ,
    GaussPairs gp, float* __restrict__ partials)
{
    const int t = threadIdx.x;
    const int lane = t & 63;
    const int wave = t >> 6;
    const int wave_id = blockIdx.x * 4 + wave;   // 0..8191

    const int l8 = 8 * lane;
    // clamped halo offsets (in floats, all dword/16B aligned as needed)
    const int oL1 = (l8 - 5 < 0) ? 0 : l8 - 5;        // tap -5 (dword)
    const int oL4 = (l8 - 4 < 0) ? 0 : l8 - 4;        // taps -4..-1 (x4)
    const int oR4 = (l8 + 8 > 504) ? 504 : l8 + 8;    // taps +8..+11 (x4)
    const int oR1 = (l8 + 12 > 508) ? 508 : l8 + 12;  // tap +12 (dword)

    const float mLs = (lane == 0) ? 0.f : 1.f;
    const float mRs = (lane == 63) ? 0.f : 1.f;
    const v2f ML = {mLs, mLs};
    const v2f MR = {mRs, mRs};

    float acc = 0.f;
    #pragma unroll
    for (int r = 0; r < 3; ++r) {
        const long long row = (long long)wave_id + 8192LL * r;   // 0..24575
        const float* prow = pred + row * 512;
        const float* qrow = targ + row * 512;

        // 12 loads: own 2x float4 + halo (dword + float4) each side, x2 inputs
        const float  pL1 = prow[oL1];
        const float4 pL4 = *reinterpret_cast<const float4*>(prow + oL4);
        const float4 pA  = *reinterpret_cast<const float4*>(prow + l8);
        const float4 pB  = *reinterpret_cast<const float4*>(prow + l8 + 4);
        const float4 pR4 = *reinterpret_cast<const float4*>(prow + oR4);
        const float  pR1 = prow[oR1];
        const float  qL1 = qrow[oL1];
        const float4 qL4 = *reinterpret_cast<const float4*>(qrow + oL4);
        const float4 qA  = *reinterpret_cast<const float4*>(qrow + l8);
        const float4 qB  = *reinterpret_cast<const float4*>(qrow + l8 + 4);
        const float4 qR4 = *reinterpret_cast<const float4*>(qrow + oR4);
        const float  qR1 = qrow[oR1];

        const float pv[18] = {pL1, pL4.x, pL4.y, pL4.z, pL4.w,
                              pA.x, pA.y, pA.z, pA.w, pB.x, pB.y, pB.z, pB.w,
                              pR4.x, pR4.y, pR4.z, pR4.w, pR1};
        const float qv[18] = {qL1, qL4.x, qL4.y, qL4.z, qL4.w,
                              qA.x, qA.y, qA.z, qA.w, qB.x, qB.y, qB.z, qB.w,
                              qR4.x, qR4.y, qR4.z, qR4.w, qR1};

        // w[i] = (u,v) at row px (8*lane - 5 + i); s[i] = (u^2, v^2)
        v2f w[18], s[18];
        #pragma unroll
        for (int i = 0; i < 18; ++i) {
            v2f wi;
            wi.x = pv[i] + qv[i];
            wi.y = pv[i] - qv[i];
            if (i < 5)       wi = pk_mul(wi, ML);   // zero-pad left edge
            else if (i >= 13) wi = pk_mul(wi, MR);  // zero-pad right edge
            w[i] = wi;
            s[i] = pk_mul(wi, wi);
        }

        #pragma unroll
        for (int px = 0; px < 8; ++px) {
            v2f AB  = {0.f, 0.f};   // (A', B') = (mu1+mu2, mu1-mu2)/sqrt2
            v2f SUV = {0.f, 0.f};   // (SU', SV') = (conv u^2, conv v^2)/2
            #pragma unroll
            for (int k = 0; k < WS; ++k) {
                AB  = pk_fma_sg(gp.gA[k], w[px + k], AB);
                SUV = pk_fma_sg(gp.gS[k], s[px + k], SUV);
            }
            const v2f ab2  = pk_mul(AB, AB);        // (A'^2, B'^2)
            const v2f t2d2 = pk_sumdiff(ab2);       // (mu1²+mu2², 2mu1mu2)
            const v2f tsds = pk_sumdiff(SUV);       // (m11+m22, 2m12)
            const v2f dn1  = pk_add_sg(t2d2, gp.c1c1);  // (den1, num1)
            const v2f dl   = pk_sub(tsds, t2d2);        // (s1+s2, 2s12)
            const v2f dn2  = pk_add_sg(dl, gp.c2c2);    // (den2, num2)
            const v2f nd   = pk_mul(dn1, dn2);          // (dd, nn)
            acc = fmaf(nd.y, __builtin_amdgcn_rcpf(nd.x), acc);
        }
    }

    // wave reduction, then block combine, partials (no atomics)
    #pragma unroll
    for (int offr = 32; offr > 0; offr >>= 1)
        acc += __shfl_down(acc, offr);
    __shared__ float wsum[4];
    if (lane == 0) wsum[wave] = acc;
    __syncthreads();
    if (t == 0)
        partials[blockIdx.x] = wsum[0] + wsum[1] + wsum[2] + wsum[3];
}

// Sum 2048 block partials in double; the 10 zero-pad rows per (b,c)
// contribute ssim == 1 exactly: 16*3*10*512 = 245760 elements.
// Total elements: 16*3*522*512 = 12828672.
__global__ __launch_bounds__(256) void ssim_final_kernel(
    const float* __restrict__ partials, float* __restrict__ out)
{
    const int t = threadIdx.x;
    double d = 0.0;
    #pragma unroll
    for (int i = 0; i < 8; ++i)
        d += (double)partials[t + 256 * i];
    #pragma unroll
    for (int offr = 32; offr > 0; offr >>= 1)
        d += __shfl_down(d, offr);
    __shared__ double wsumd[4];
    const int lane = t & 63, wave = t >> 6;
    if (lane == 0) wsumd[wave] = d;
    __syncthreads();
    if (t == 0) {
        const double s = wsumd[0] + wsumd[1] + wsumd[2] + wsumd[3] + 245760.0;
        out[0] = (float)(1.0 - s / 12828672.0);
    }
}

static unsigned long long pack2(float x) {
    unsigned int b;
    __builtin_memcpy(&b, &x, 4);
    return ((unsigned long long)b << 32) | b;
}

extern "C" void kernel_launch(void* const* d_in, const int* in_sizes, int n_in,
                              void* d_out, int out_size, void* d_ws, size_t ws_size,
                              hipStream_t stream) {
    const float* pred = (const float*)d_in[0];
    const float* targ = (const float*)d_in[1];
    float* out = (float*)d_out;
    float* partials = (float*)d_ws;   // 2048 floats

    // Gaussian window exactly as the reference (sigma=1.5, ws=11),
    // prescaled: gA = g/sqrt(2) (linear chain), gS = g/2 (square chain).
    GaussPairs gp;
    double graw[WS], s = 0.0;
    for (int i = 0; i < WS; ++i) {
        const double c = (double)(i - WS / 2);
        graw[i] = exp(-c * c / (2.0 * 1.5 * 1.5));
        s += graw[i];
    }
    for (int i = 0; i < WS; ++i) {
        const double g = graw[i] / s;
        gp.gA[i] = pack2((float)(g * 0.70710678118654752));
        gp.gS[i] = pack2((float)(g * 0.5));
    }
    gp.c1c1 = pack2(0.0001f);
    gp.c2c2 = pack2(0.0009f);

    ssim_row_kernel<<<2048, 256, 0, stream>>>(pred, targ, gp, partials);
    ssim_final_kernel<<<1, 256, 0, stream>>>(partials, out);
}

// Round 8
// 29.163 us; speedup vs baseline: 1.0349x; 1.0349x over previous
//
#include <hip/hip_runtime.h>
#include <cmath>

#define WS 11
#define ROWSTRIDE 4194304LL   // 8192 rows * 512 floats between r-iterations

typedef float v2f __attribute__((ext_vector_type(2)));

struct GaussPairs {
    unsigned long long gA[WS];   // (g/sqrt2, g/sqrt2) — linear chain
    unsigned long long gS[WS];   // (g/2, g/2)         — square chain
    unsigned long long c1c1;     // (C1, C1)
    unsigned long long c2c2;     // (C2, C2)
};

// ---- VOP3P packed-f32 helpers (gfx90a+/gfx950) ----
__device__ __forceinline__ v2f pk_fma_sg(unsigned long long g, v2f b, v2f c) {
    v2f d;
    asm("v_pk_fma_f32 %0, %1, %2, %3" : "=v"(d) : "s"(g), "v"(b), "v"(c));
    return d;
}
__device__ __forceinline__ v2f pk_mul(v2f a, v2f b) {
    v2f d;
    asm("v_pk_mul_f32 %0, %1, %2" : "=v"(d) : "v"(a), "v"(b));
    return d;
}
// (a.x+a.y, a.x-a.y)
__device__ __forceinline__ v2f pk_sumdiff(v2f a) {
    v2f d;
    asm("v_pk_add_f32 %0, %1, %1 op_sel:[0,1] op_sel_hi:[0,1] neg_hi:[0,1]"
        : "=v"(d) : "v"(a));
    return d;
}
__device__ __forceinline__ v2f pk_add_sg(v2f a, unsigned long long c) {
    v2f d;
    asm("v_pk_add_f32 %0, %1, %2" : "=v"(d) : "v"(a), "s"(c));
    return d;
}
__device__ __forceinline__ v2f pk_sub(v2f a, v2f b) {
    v2f d;
    asm("v_pk_add_f32 %0, %1, %2 neg_lo:[0,1] neg_hi:[0,1]"
        : "=v"(d) : "v"(a), "v"(b));
    return d;
}

struct RowRegs {
    float4 pL4, pA, pB, pR4, qL4, qA, qB, qR4;
    float  pL1, pR1, qL1, qR1;
};

__device__ __forceinline__ RowRegs load_row(
    const float* __restrict__ prow, const float* __restrict__ qrow,
    int oL1, int oL4, int l8, int oR4, int oR1)
{
    RowRegs R;
    R.pL1 = prow[oL1];
    R.pL4 = *reinterpret_cast<const float4*>(prow + oL4);
    R.pA  = *reinterpret_cast<const float4*>(prow + l8);
    R.pB  = *reinterpret_cast<const float4*>(prow + l8 + 4);
    R.pR4 = *reinterpret_cast<const float4*>(prow + oR4);
    R.pR1 = prow[oR1];
    R.qL1 = qrow[oL1];
    R.qL4 = *reinterpret_cast<const float4*>(qrow + oL4);
    R.qA  = *reinterpret_cast<const float4*>(qrow + l8);
    R.qB  = *reinterpret_cast<const float4*>(qrow + l8 + 4);
    R.qR4 = *reinterpret_cast<const float4*>(qrow + oR4);
    R.qR1 = qrow[oR1];
    return R;
}

__device__ __forceinline__ float compute_row(
    const RowRegs& R, const GaussPairs& gp, v2f ML, v2f MR)
{
    const float pv[18] = {R.pL1, R.pL4.x, R.pL4.y, R.pL4.z, R.pL4.w,
                          R.pA.x, R.pA.y, R.pA.z, R.pA.w,
                          R.pB.x, R.pB.y, R.pB.z, R.pB.w,
                          R.pR4.x, R.pR4.y, R.pR4.z, R.pR4.w, R.pR1};
    const float qv[18] = {R.qL1, R.qL4.x, R.qL4.y, R.qL4.z, R.qL4.w,
                          R.qA.x, R.qA.y, R.qA.z, R.qA.w,
                          R.qB.x, R.qB.y, R.qB.z, R.qB.w,
                          R.qR4.x, R.qR4.y, R.qR4.z, R.qR4.w, R.qR1};

    // w[i] = (u,v) at row px (8*lane - 5 + i); s[i] = (u^2, v^2)
    v2f w[18], s[18];
    #pragma unroll
    for (int i = 0; i < 18; ++i) {
        v2f wi;
        wi.x = pv[i] + qv[i];
        wi.y = pv[i] - qv[i];
        if (i < 5)        wi = pk_mul(wi, ML);   // zero-pad left edge
        else if (i >= 13) wi = pk_mul(wi, MR);   // zero-pad right edge
        w[i] = wi;
        s[i] = pk_mul(wi, wi);
    }

    float acc = 0.f;
    #pragma unroll
    for (int px = 0; px < 8; ++px) {
        v2f AB  = {0.f, 0.f};   // (mu1+mu2, mu1-mu2)/sqrt2
        v2f SUV = {0.f, 0.f};   // (conv u^2, conv v^2)/2
        #pragma unroll
        for (int k = 0; k < WS; ++k) {
            AB  = pk_fma_sg(gp.gA[k], w[px + k], AB);
            SUV = pk_fma_sg(gp.gS[k], s[px + k], SUV);
        }
        const v2f ab2  = pk_mul(AB, AB);            // (A'^2, B'^2)
        const v2f t2d2 = pk_sumdiff(ab2);           // (mu1²+mu2², 2mu1mu2)
        const v2f tsds = pk_sumdiff(SUV);           // (m11+m22, 2m12)
        const v2f dn1  = pk_add_sg(t2d2, gp.c1c1);  // (den1, num1)
        const v2f dl   = pk_sub(tsds, t2d2);        // (s1+s2, 2s12)
        const v2f dn2  = pk_add_sg(dl, gp.c2c2);    // (den2, num2)
        const v2f nd   = pk_mul(dn1, dn2);          // (dd, nn)
        acc = fmaf(nd.y, __builtin_amdgcn_rcpf(nd.x), acc);
    }
    return acc;
}

// 24576 rows x 512 floats. One wave per row, 8 px/lane, 3 rows/wave,
// software-pipelined: issue row r+1's loads before computing row r.
// Halos via overlapping global loads (L1), edges zeroed by mask pairs.
__global__ __launch_bounds__(256, 4) void ssim_row_kernel(
    const float* __restrict__ pred, const float* __restrict__ targ,
    GaussPairs gp, float* __restrict__ partials)
{
    const int t = threadIdx.x;
    const int lane = t & 63;
    const int wave = t >> 6;
    const int wave_id = blockIdx.x * 4 + wave;   // 0..8191

    const int l8 = 8 * lane;
    const int oL1 = (l8 - 5 < 0) ? 0 : l8 - 5;        // tap -5 (dword)
    const int oL4 = (l8 - 4 < 0) ? 0 : l8 - 4;        // taps -4..-1 (x4)
    const int oR4 = (l8 + 8 > 504) ? 504 : l8 + 8;    // taps +8..+11 (x4)
    const int oR1 = (l8 + 12 > 508) ? 508 : l8 + 12;  // tap +12 (dword)

    const float mLs = (lane == 0) ? 0.f : 1.f;
    const float mRs = (lane == 63) ? 0.f : 1.f;
    const v2f ML = {mLs, mLs};
    const v2f MR = {mRs, mRs};

    const float* pbase = pred + (long long)wave_id * 512;
    const float* qbase = targ + (long long)wave_id * 512;

    // software pipeline over the wave's 3 rows (static indexing throughout)
    RowRegs r0 = load_row(pbase, qbase, oL1, oL4, l8, oR4, oR1);
    RowRegs r1 = load_row(pbase + ROWSTRIDE, qbase + ROWSTRIDE,
                          oL1, oL4, l8, oR4, oR1);
    float acc = compute_row(r0, gp, ML, MR);
    RowRegs r2 = load_row(pbase + 2 * ROWSTRIDE, qbase + 2 * ROWSTRIDE,
                          oL1, oL4, l8, oR4, oR1);
    acc += compute_row(r1, gp, ML, MR);
    acc += compute_row(r2, gp, ML, MR);

    // wave reduction, then block combine, partials (no atomics)
    #pragma unroll
    for (int offr = 32; offr > 0; offr >>= 1)
        acc += __shfl_down(acc, offr);
    __shared__ float wsum[4];
    if (lane == 0) wsum[wave] = acc;
    __syncthreads();
    if (t == 0)
        partials[blockIdx.x] = wsum[0] + wsum[1] + wsum[2] + wsum[3];
}

// Sum 2048 block partials in double; the 10 zero-pad rows per (b,c)
// contribute ssim == 1 exactly: 16*3*10*512 = 245760 elements.
// Total elements: 16*3*522*512 = 12828672.
__global__ __launch_bounds__(256) void ssim_final_kernel(
    const float* __restrict__ partials, float* __restrict__ out)
{
    const int t = threadIdx.x;
    double d = 0.0;
    #pragma unroll
    for (int i = 0; i < 8; ++i)
        d += (double)partials[t + 256 * i];
    #pragma unroll
    for (int offr = 32; offr > 0; offr >>= 1)
        d += __shfl_down(d, offr);
    __shared__ double wsumd[4];
    const int lane = t & 63, wave = t >> 6;
    if (lane == 0) wsumd[wave] = d;
    __syncthreads();
    if (t == 0) {
        const double s = wsumd[0] + wsumd[1] + wsumd[2] + wsumd[3] + 245760.0;
        out[0] = (float)(1.0 - s / 12828672.0);
    }
}

static unsigned long long pack2(float x) {
    unsigned int b;
    __builtin_memcpy(&b, &x, 4);
    return ((unsigned long long)b << 32) | b;
}

extern "C" void kernel_launch(void* const* d_in, const int* in_sizes, int n_in,
                              void* d_out, int out_size, void* d_ws, size_t ws_size,
                              hipStream_t stream) {
    const float* pred = (const float*)d_in[0];
    const float* targ = (const float*)d_in[1];
    float* out = (float*)d_out;
    float* partials = (float*)d_ws;   // 2048 floats

    // Gaussian window exactly as the reference (sigma=1.5, ws=11),
    // prescaled: gA = g/sqrt(2) (linear chain), gS = g/2 (square chain).
    GaussPairs gp;
    double graw[WS], s = 0.0;
    for (int i = 0; i < WS; ++i) {
        const double c = (double)(i - WS / 2);
        graw[i] = exp(-c * c / (2.0 * 1.5 * 1.5));
        s += graw[i];
    }
    for (int i = 0; i < WS; ++i) {
        const double g = graw[i] / s;
        gp.gA[i] = pack2((float)(g * 0.70710678118654752));
        gp.gS[i] = pack2((float)(g * 0.5));
    }
    gp.c1c1 = pack2(0.0001f);
    gp.c2c2 = pack2(0.0009f);

    ssim_row_kernel<<<2048, 256, 0, stream>>>(pred, targ, gp, partials);
    ssim_final_kernel<<<1, 256, 0, stream>>>(partials, out);
}

// Round 9
// 29.073 us; speedup vs baseline: 1.0381x; 1.0031x over previous
//
#include <hip/hip_runtime.h>
#include <cmath>

#define WS 11

typedef float v2f __attribute__((ext_vector_type(2)));
typedef unsigned int u32x4_t __attribute__((ext_vector_type(4)));

struct GaussPairs {
    unsigned long long gA[WS];   // (g/sqrt2, g/sqrt2) — linear chain
    unsigned long long gS[WS];   // (g/2, g/2)         — square chain
    unsigned long long c1c1;     // (C1, C1)
    unsigned long long c2c2;     // (C2, C2)
};

// ---- VOP3P packed-f32 helpers (gfx90a+/gfx950) ----
__device__ __forceinline__ v2f pk_fma_sg(unsigned long long g, v2f b, v2f c) {
    v2f d;
    asm("v_pk_fma_f32 %0, %1, %2, %3" : "=v"(d) : "s"(g), "v"(b), "v"(c));
    return d;
}
__device__ __forceinline__ v2f pk_mul(v2f a, v2f b) {
    v2f d;
    asm("v_pk_mul_f32 %0, %1, %2" : "=v"(d) : "v"(a), "v"(b));
    return d;
}
// (a.x+a.y, a.x-a.y)
__device__ __forceinline__ v2f pk_sumdiff(v2f a) {
    v2f d;
    asm("v_pk_add_f32 %0, %1, %1 op_sel:[0,1] op_sel_hi:[0,1] neg_hi:[0,1]"
        : "=v"(d) : "v"(a));
    return d;
}
__device__ __forceinline__ v2f pk_add_sg(v2f a, unsigned long long c) {
    v2f d;
    asm("v_pk_add_f32 %0, %1, %2" : "=v"(d) : "v"(a), "s"(c));
    return d;
}
__device__ __forceinline__ v2f pk_sub(v2f a, v2f b) {
    v2f d;
    asm("v_pk_add_f32 %0, %1, %2 neg_lo:[0,1] neg_hi:[0,1]"
        : "=v"(d) : "v"(a), "v"(b));
    return d;
}

// ---- raw buffer loads against a per-row SRD (num_records = 2048 bytes).
// OOB voffsets (negative or >= 2048-access) return 0 in hardware — this IS
// the reference's W zero-padding, for free. All boundary accesses are fully
// in-bounds or fully OOB (16B segments tile the 2048B row exactly).
__device__ __forceinline__ u32x4_t make_row_srsrc(const float* p) {
    const unsigned long long a = (unsigned long long)p;
    u32x4_t r;
    r.x = (unsigned)a;
    r.y = (unsigned)(a >> 32);
    r.z = 2048u;          // num_records (bytes, stride==0)
    r.w = 0x00020000u;    // raw untyped dword access
    return r;
}
__device__ __forceinline__ float4 bl_x4(u32x4_t srd, int voff) {
    float4 d;
    asm volatile("buffer_load_dwordx4 %0, %1, %2, 0 offen"
                 : "=v"(d) : "v"(voff), "s"(srd));
    return d;
}
__device__ __forceinline__ float bl_x1(u32x4_t srd, int voff) {
    float d;
    asm volatile("buffer_load_dword %0, %1, %2, 0 offen"
                 : "=v"(d) : "v"(voff), "s"(srd));
    return d;
}

// 24576 rows x 512 floats. ONE wave per row (8 px/lane), 6144 blocks of 256:
// 3x block oversubscription gives load/compute phase diversity across the CU.
// No LDS, no barriers, no edge masks; per-wave partial written by lane 0.
__global__ __launch_bounds__(256) void ssim_row_kernel(
    const float* __restrict__ pred, const float* __restrict__ targ,
    GaussPairs gp, float* __restrict__ partials)
{
    const int t = threadIdx.x;
    const int lane = t & 63;
    // wave-uniform row id, forced scalar
    const int wid = __builtin_amdgcn_readfirstlane((blockIdx.x << 2) | (t >> 6));

    const int l8 = 8 * lane;
    const int vL1 = 4 * (l8 - 5);    // tap -5 (dword; OOB->0 at lane 0)
    const int vL4 = 4 * (l8 - 4);    // taps -4..-1
    const int vA  = 4 * l8;          // taps  0..3
    const int vB  = 4 * (l8 + 4);    // taps  4..7
    const int vR4 = 4 * (l8 + 8);    // taps  8..11 (OOB->0 at lane 63)
    const int vR1 = 4 * (l8 + 12);   // tap  12

    const u32x4_t sp = make_row_srsrc(pred + (long long)wid * 512);
    const u32x4_t sq = make_row_srsrc(targ + (long long)wid * 512);

    const float  pL1 = bl_x1(sp, vL1);
    const float4 pL4 = bl_x4(sp, vL4);
    const float4 pA  = bl_x4(sp, vA);
    const float4 pB  = bl_x4(sp, vB);
    const float4 pR4 = bl_x4(sp, vR4);
    const float  pR1 = bl_x1(sp, vR1);
    const float  qL1 = bl_x1(sq, vL1);
    const float4 qL4 = bl_x4(sq, vL4);
    const float4 qA  = bl_x4(sq, vA);
    const float4 qB  = bl_x4(sq, vB);
    const float4 qR4 = bl_x4(sq, vR4);
    const float  qR1 = bl_x1(sq, vR1);
    asm volatile("s_waitcnt vmcnt(0)" ::: "memory");
    __builtin_amdgcn_sched_barrier(0);

    const float pv[18] = {pL1, pL4.x, pL4.y, pL4.z, pL4.w,
                          pA.x, pA.y, pA.z, pA.w, pB.x, pB.y, pB.z, pB.w,
                          pR4.x, pR4.y, pR4.z, pR4.w, pR1};
    const float qv[18] = {qL1, qL4.x, qL4.y, qL4.z, qL4.w,
                          qA.x, qA.y, qA.z, qA.w, qB.x, qB.y, qB.z, qB.w,
                          qR4.x, qR4.y, qR4.z, qR4.w, qR1};

    // w[i] = (u,v) at row px (8*lane - 5 + i); s[i] = (u^2, v^2)
    v2f w[18], s[18];
    #pragma unroll
    for (int i = 0; i < 18; ++i) {
        v2f wi;
        wi.x = pv[i] + qv[i];
        wi.y = pv[i] - qv[i];
        w[i] = wi;
        s[i] = pk_mul(wi, wi);
    }

    float acc = 0.f;
    #pragma unroll
    for (int px = 0; px < 8; ++px) {
        v2f AB  = {0.f, 0.f};   // (mu1+mu2, mu1-mu2)/sqrt2
        v2f SUV = {0.f, 0.f};   // (conv u^2, conv v^2)/2
        #pragma unroll
        for (int k = 0; k < WS; ++k) {
            AB  = pk_fma_sg(gp.gA[k], w[px + k], AB);
            SUV = pk_fma_sg(gp.gS[k], s[px + k], SUV);
        }
        const v2f ab2  = pk_mul(AB, AB);            // (A'^2, B'^2)
        const v2f t2d2 = pk_sumdiff(ab2);           // (mu1²+mu2², 2mu1mu2)
        const v2f tsds = pk_sumdiff(SUV);           // (m11+m22, 2m12)
        const v2f dn1  = pk_add_sg(t2d2, gp.c1c1);  // (den1, num1)
        const v2f dl   = pk_sub(tsds, t2d2);        // (s1+s2, 2s12)
        const v2f dn2  = pk_add_sg(dl, gp.c2c2);    // (den2, num2)
        const v2f nd   = pk_mul(dn1, dn2);          // (dd, nn)
        acc = fmaf(nd.y, __builtin_amdgcn_rcpf(nd.x), acc);
    }

    // wave shuffle reduction; lane 0 writes this row's partial. No barriers.
    #pragma unroll
    for (int offr = 32; offr > 0; offr >>= 1)
        acc += __shfl_down(acc, offr);
    if (lane == 0)
        partials[wid] = acc;
}

// Sum 24576 per-row partials in double; the 10 zero-pad rows per (b,c)
// contribute ssim == 1 exactly: 16*3*10*512 = 245760 elements.
// Total elements: 16*3*522*512 = 12828672.
__global__ __launch_bounds__(1024) void ssim_final_kernel(
    const float* __restrict__ partials, float* __restrict__ out)
{
    const int t = threadIdx.x;
    double d = 0.0;
    #pragma unroll
    for (int i = 0; i < 24; ++i)
        d += (double)partials[t + 1024 * i];
    #pragma unroll
    for (int offr = 32; offr > 0; offr >>= 1)
        d += __shfl_down(d, offr);
    __shared__ double wsumd[16];
    const int lane = t & 63, wave = t >> 6;
    if (lane == 0) wsumd[wave] = d;
    __syncthreads();
    if (t == 0) {
        double s = 245760.0;
        #pragma unroll
        for (int i = 0; i < 16; ++i) s += wsumd[i];
        out[0] = (float)(1.0 - s / 12828672.0);
    }
}

static unsigned long long pack2(float x) {
    unsigned int b;
    __builtin_memcpy(&b, &x, 4);
    return ((unsigned long long)b << 32) | b;
}

extern "C" void kernel_launch(void* const* d_in, const int* in_sizes, int n_in,
                              void* d_out, int out_size, void* d_ws, size_t ws_size,
                              hipStream_t stream) {
    const float* pred = (const float*)d_in[0];
    const float* targ = (const float*)d_in[1];
    float* out = (float*)d_out;
    float* partials = (float*)d_ws;   // 24576 floats

    // Gaussian window exactly as the reference (sigma=1.5, ws=11),
    // prescaled: gA = g/sqrt(2) (linear chain), gS = g/2 (square chain).
    GaussPairs gp;
    double graw[WS], s = 0.0;
    for (int i = 0; i < WS; ++i) {
        const double c = (double)(i - WS / 2);
        graw[i] = exp(-c * c / (2.0 * 1.5 * 1.5));
        s += graw[i];
    }
    for (int i = 0; i < WS; ++i) {
        const double g = graw[i] / s;
        gp.gA[i] = pack2((float)(g * 0.70710678118654752));
        gp.gS[i] = pack2((float)(g * 0.5));
    }
    gp.c1c1 = pack2(0.0001f);
    gp.c2c2 = pack2(0.0009f);

    ssim_row_kernel<<<6144, 256, 0, stream>>>(pred, targ, gp, partials);
    ssim_final_kernel<<<1, 1024, 0, stream>>>(partials, out);
}